// Round 17
// baseline (85.433 us; speedup 1.0000x reference)
//
#include <hip/hip_runtime.h>
#include <hip/hip_bf16.h>

#define BATCH 2
#define CH 256
#define HW 4096
#define HEADS 8
#define HDIM 32
#define GROUPS 32
#define EPS 1e-5f
#define QSCALE (0.17677669529663687f * 1.4426950408889634f)  // scale * log2(e)

typedef short s16x8 __attribute__((ext_vector_type(8)));
typedef float floatx4 __attribute__((ext_vector_type(4)));
typedef unsigned short ushort_t;
typedef unsigned int uint_t;

static __device__ __forceinline__ ushort_t f2bf(float f) {
    __hip_bfloat16 h = __float2bfloat16(f);
    return *reinterpret_cast<ushort_t*>(&h);
}

// pack two f32 -> one u32 of 2 bf16 (truncation) via single v_perm_b32
static __device__ __forceinline__ uint_t pk2(float lo, float hi) {
    return __builtin_amdgcn_perm(__float_as_uint(hi), __float_as_uint(lo), 0x07060302u);
}

static __device__ __forceinline__ void gload_lds16(const ushort_t* g, ushort_t* l) {
    __builtin_amdgcn_global_load_lds((const __attribute__((address_space(1))) void*)g,
                                     (__attribute__((address_space(3))) void*)l, 16, 0, 0);
}

// ---------------- Kernel 1: groupnorm stats + weight convert (fused launch) ----------------
__global__ void gn_stats_wcvt(const float* __restrict__ x, float* __restrict__ stats,
                              const float* __restrict__ wq, const float* __restrict__ wo,
                              ushort_t* __restrict__ wdst) {
    if (blockIdx.x >= 64) {
        int i = (blockIdx.x - 64) * 256 + threadIdx.x;  // 65536 lanes, 4 floats each
        float4 v = (i < 49152) ? ((const float4*)wq)[i] : ((const float4*)wo)[i - 49152];
        ushort_t p[4] = {f2bf(v.x), f2bf(v.y), f2bf(v.z), f2bf(v.w)};
        uint2 o;
        o.x = (uint_t)p[0] | ((uint_t)p[1] << 16);
        o.y = (uint_t)p[2] | ((uint_t)p[3] << 16);
        *(uint2*)&wdst[(size_t)i * 4] = o;
        return;
    }
    int bg = blockIdx.x;
    const float4* xv = (const float4*)(x + (size_t)bg * 8 * HW);
    int t = threadIdx.x;
    float s = 0.f, ss = 0.f;
    for (int i = t; i < 8192; i += 256) {
        float4 v = xv[i];
        s  += v.x + v.y + v.z + v.w;
        ss += v.x*v.x + v.y*v.y + v.z*v.z + v.w*v.w;
    }
    #pragma unroll
    for (int off = 32; off; off >>= 1) {
        s  += __shfl_down(s, off);
        ss += __shfl_down(ss, off);
    }
    __shared__ float rs[4], rss[4];
    int wave = t >> 6;
    if ((t & 63) == 0) { rs[wave] = s; rss[wave] = ss; }
    __syncthreads();
    if (t == 0) {
        s  = rs[0] + rs[1] + rs[2] + rs[3];
        ss = rss[0] + rss[1] + rss[2] + rss[3];
        float mu  = s / 32768.f;
        float var = ss / 32768.f - mu * mu;
        stats[bg * 2]     = mu;
        stats[bg * 2 + 1] = rsqrtf(var + EPS);
    }
}

// ---------------- Kernel 2: normalize + transpose to [b][n][c] bf16 ----------------
__global__ void norm_transpose(const float* __restrict__ x, const float* __restrict__ stats,
                               const float* __restrict__ gw, const float* __restrict__ gb,
                               ushort_t* __restrict__ xn) {
    __shared__ ushort_t tile[64][40];
    int b = blockIdx.z, c0 = blockIdx.y * 32, n0 = blockIdx.x * 64;
    int t = threadIdx.x;
    #pragma unroll
    for (int i = 0; i < 8; i++) {
        int idx = i * 256 + t;
        int c = idx >> 6, n = idx & 63;
        int cc = c0 + c;
        float mu   = stats[(b * GROUPS + (cc >> 3)) * 2];
        float rstd = stats[(b * GROUPS + (cc >> 3)) * 2 + 1];
        float v = x[((size_t)b * CH + cc) * HW + n0 + n];
        v = (v - mu) * rstd * gw[cc] + gb[cc];
        tile[n][c] = f2bf(v);
    }
    __syncthreads();
    int n = t >> 2, chk = t & 3;
    uint4 val = *(const uint4*)&tile[n][chk * 8];
    *(uint4*)(xn + ((size_t)(b * HW + n0 + n)) * CH + c0 + chk * 8) = val;
}

// ---------------- Kernel 3: QKV gemm (bf16 weights, o-tile 128, reg-prefetch) ----------------
__global__ void qkv_gemm(const ushort_t* __restrict__ xn, const ushort_t* __restrict__ wqb,
                         ushort_t* __restrict__ qo, ushort_t* __restrict__ ko,
                         ushort_t* __restrict__ vo) {
    __shared__ ushort_t Al[64][40];
    __shared__ ushort_t Bl[128][40];
    int b = blockIdx.z;
    int n0 = blockIdx.x * 64, o0 = blockIdx.y * 128;
    int t = threadIdx.x, lane = t & 63, wave = t >> 6;
    int lr = lane & 15, lk = lane >> 4;
    int row = t >> 2, chk = t & 3;
    const ushort_t* asrc = xn + ((size_t)(b * HW + n0 + row)) * CH + chk * 8;
    int s1 = t + 256;
    const ushort_t* bsrc0 = wqb + (size_t)(o0 + (t >> 2)) * CH + (t & 3) * 8;
    const ushort_t* bsrc1 = wqb + (size_t)(o0 + (s1 >> 2)) * CH + (s1 & 3) * 8;
    floatx4 acc[8] = {};
    uint4 ra  = *(const uint4*)(asrc);
    uint4 rb0 = *(const uint4*)(bsrc0);
    uint4 rb1 = *(const uint4*)(bsrc1);
    for (int k0 = 0; k0 < 8; k0++) {
        *(uint4*)&Al[row][chk * 8] = ra;
        *(uint4*)&Bl[t >> 2][(t & 3) * 8] = rb0;
        *(uint4*)&Bl[s1 >> 2][(s1 & 3) * 8] = rb1;
        __syncthreads();
        if (k0 < 7) {  // prefetch next chunk; latency hides under MFMAs
            ra  = *(const uint4*)(asrc + (k0 + 1) * 32);
            rb0 = *(const uint4*)(bsrc0 + (k0 + 1) * 32);
            rb1 = *(const uint4*)(bsrc1 + (k0 + 1) * 32);
        }
        s16x8 af = *(const s16x8*)&Al[wave * 16 + lr][lk * 8];
        #pragma unroll
        for (int ct = 0; ct < 8; ct++) {
            s16x8 bf = *(const s16x8*)&Bl[ct * 16 + lr][lk * 8];
            acc[ct] = __builtin_amdgcn_mfma_f32_16x16x32_bf16(af, bf, acc[ct], 0, 0, 0);
        }
        __syncthreads();
    }
    #pragma unroll
    for (int ct = 0; ct < 8; ct++) {
        int o = o0 + ct * 16 + lr;
        int sel = o >> 8;
        int h = (o >> 5) & 7;
        int d = o & 31;
        int nrow0 = n0 + wave * 16 + (lk << 2);
        if (sel == 0) {
            #pragma unroll
            for (int r = 0; r < 4; r++)
                qo[(((size_t)(b * HEADS + h)) * HW + nrow0 + r) * HDIM + d] =
                    f2bf(acc[ct][r] * QSCALE);
        } else if (sel == 1) {
            #pragma unroll
            for (int r = 0; r < 4; r++) {
                int tt = (nrow0 + r) & 63;
                int sg = 4 * ((tt >> 3) & 3) + 16 * ((((tt >> 2) & 1) << 1) | ((tt >> 5) & 1)) + (tt & 3);
                ko[(((size_t)(b * HEADS + h)) * HW + n0 + sg) * HDIM + d] = f2bf(acc[ct][r]);
            }
        } else {
            ushort_t pk[4];
            #pragma unroll
            for (int r = 0; r < 4; r++) pk[r] = f2bf(acc[ct][r]);
            *(uint2*)&vo[(((size_t)(b * HEADS + h)) * HDIM + d) * HW + nrow0] = *(uint2*)pk;
        }
    }
}

// ---------------- Kernel 4: flash attention (QBLK=128, K-split x2 — best measured) ----------------
__global__ void __launch_bounds__(256, 4)
attn_f(const ushort_t* __restrict__ qg, const ushort_t* __restrict__ kg,
       const ushort_t* __restrict__ vg, ushort_t* __restrict__ op0,
       ushort_t* __restrict__ op1, float* __restrict__ lpart) {
    __shared__ ushort_t Kl[2][2048];  // lane-ordered, 4KB/buf
    __shared__ ushort_t Vl[2][2048];
    const int bh = blockIdx.y;
    const int z = blockIdx.z;
    const int n0 = blockIdx.x * 128;
    const int t = threadIdx.x;
    const int lane = t & 63, w = t >> 6;
    const int lr = lane & 15, lk = lane >> 4;

    const ushort_t* kb = kg + (size_t)bh * HW * HDIM + (size_t)z * 2048 * HDIM;
    const ushort_t* vb = vg + (size_t)bh * HDIM * HW + z * 2048;

    const int lrr = t & 15, lkk = (t >> 4) & 3, wv = t >> 6;
    const ushort_t* gk = kb + ((wv << 4) + lrr) * HDIM + lkk * 8;
    const ushort_t* gv = vb + (size_t)(((t >> 7) << 4) + lrr) * HW + ((t >> 6) & 1) * 32 + lkk * 8;
    ushort_t* kd0 = &Kl[0][wv << 9]; ushort_t* kd1 = &Kl[1][wv << 9];
    ushort_t* vd0 = &Vl[0][wv << 9]; ushort_t* vd1 = &Vl[1][wv << 9];

    s16x8 qf0 = *(const s16x8*)(qg + ((size_t)bh * HW + n0 + w * 16 + lr) * HDIM + lk * 8);
    s16x8 qf1 = *(const s16x8*)(qg + ((size_t)bh * HW + n0 + 64 + w * 16 + lr) * HDIM + lk * 8);

    const s16x8 onesf = {0x3F80, 0x3F80, 0x3F80, 0x3F80, 0x3F80, 0x3F80, 0x3F80, 0x3F80};
    const floatx4 zf = {};
    floatx4 oacc[2][2] = {};   // [frag][ct2]
    floatx4 Lacc[2] = {};

    auto stage = [&](ushort_t* kdn, ushort_t* vdn) {
        gload_lds16(gk, kdn);
        gload_lds16(gv, vdn);
        gk += 64 * HDIM; gv += 64;
    };
    auto compute = [&](const ushort_t* Kb, const ushort_t* Vb) {
        floatx4 sim0[4], sim1[4];
        __builtin_amdgcn_s_setprio(1);
#pragma unroll
        for (int ct = 0; ct < 4; ct++) {
            s16x8 kf = *(const s16x8*)(Kb + ct * 512 + lane * 8);
            sim0[ct] = __builtin_amdgcn_mfma_f32_16x16x32_bf16(kf, qf0, zf, 0, 0, 0);
            sim1[ct] = __builtin_amdgcn_mfma_f32_16x16x32_bf16(kf, qf1, zf, 0, 0, 0);
        }
        __builtin_amdgcn_s_setprio(0);
        s16x8 vf[4];
#pragma unroll
        for (int i = 0; i < 4; i++)
            vf[i] = *(const s16x8*)(Vb + i * 512 + lane * 8);
        // fragment 0
        {
            s16x8 pf[2];
#pragma unroll
            for (int s = 0; s < 2; s++) {
                union { uint_t u[4]; s16x8 v; } pu;
                pu.u[0] = pk2(__builtin_amdgcn_exp2f(sim0[s][0]),     __builtin_amdgcn_exp2f(sim0[s][1]));
                pu.u[1] = pk2(__builtin_amdgcn_exp2f(sim0[s][2]),     __builtin_amdgcn_exp2f(sim0[s][3]));
                pu.u[2] = pk2(__builtin_amdgcn_exp2f(sim0[s + 2][0]), __builtin_amdgcn_exp2f(sim0[s + 2][1]));
                pu.u[3] = pk2(__builtin_amdgcn_exp2f(sim0[s + 2][2]), __builtin_amdgcn_exp2f(sim0[s + 2][3]));
                pf[s] = pu.v;
            }
            __builtin_amdgcn_s_setprio(1);
#pragma unroll
            for (int s = 0; s < 2; s++) {
                oacc[0][0] = __builtin_amdgcn_mfma_f32_16x16x32_bf16(vf[s],     pf[s], oacc[0][0], 0, 0, 0);
                oacc[0][1] = __builtin_amdgcn_mfma_f32_16x16x32_bf16(vf[2 + s], pf[s], oacc[0][1], 0, 0, 0);
                Lacc[0]    = __builtin_amdgcn_mfma_f32_16x16x32_bf16(onesf,     pf[s], Lacc[0],    0, 0, 0);
            }
            __builtin_amdgcn_s_setprio(0);
        }
        // fragment 1
        {
            s16x8 pf[2];
#pragma unroll
            for (int s = 0; s < 2; s++) {
                union { uint_t u[4]; s16x8 v; } pu;
                pu.u[0] = pk2(__builtin_amdgcn_exp2f(sim1[s][0]),     __builtin_amdgcn_exp2f(sim1[s][1]));
                pu.u[1] = pk2(__builtin_amdgcn_exp2f(sim1[s][2]),     __builtin_amdgcn_exp2f(sim1[s][3]));
                pu.u[2] = pk2(__builtin_amdgcn_exp2f(sim1[s + 2][0]), __builtin_amdgcn_exp2f(sim1[s + 2][1]));
                pu.u[3] = pk2(__builtin_amdgcn_exp2f(sim1[s + 2][2]), __builtin_amdgcn_exp2f(sim1[s + 2][3]));
                pf[s] = pu.v;
            }
            __builtin_amdgcn_s_setprio(1);
#pragma unroll
            for (int s = 0; s < 2; s++) {
                oacc[1][0] = __builtin_amdgcn_mfma_f32_16x16x32_bf16(vf[s],     pf[s], oacc[1][0], 0, 0, 0);
                oacc[1][1] = __builtin_amdgcn_mfma_f32_16x16x32_bf16(vf[2 + s], pf[s], oacc[1][1], 0, 0, 0);
                Lacc[1]    = __builtin_amdgcn_mfma_f32_16x16x32_bf16(onesf,     pf[s], Lacc[1],    0, 0, 0);
            }
            __builtin_amdgcn_s_setprio(0);
        }
    };

    stage(kd0, vd0);
    __syncthreads();
    for (int s2 = 0; s2 < 16; s2++) {
        stage(kd1, vd1);
        compute(&Kl[0][0], &Vl[0][0]);
        __syncthreads();
        if (s2 < 15) {
            stage(kd0, vd0);
            compute(&Kl[1][0], &Vl[1][0]);
            __syncthreads();
        } else {
            compute(&Kl[1][0], &Vl[1][0]);
        }
    }

    ushort_t* ob = (z ? op1 : op0) + ((size_t)bh * HW) * 32;
    float* lp = lpart + (size_t)(z * 16 + bh) * HW;
#pragma unroll
    for (int c = 0; c < 2; c++) {
        int n = n0 + c * 64 + w * 16 + lr;
        if (lk == 0) lp[n] = Lacc[c][0];
#pragma unroll
        for (int ct2 = 0; ct2 < 2; ct2++) {
            uint_t lo = (uint_t)f2bf(oacc[c][ct2][0]) | ((uint_t)f2bf(oacc[c][ct2][1]) << 16);
            uint_t hi = (uint_t)f2bf(oacc[c][ct2][2]) | ((uint_t)f2bf(oacc[c][ct2][3]) << 16);
            uint2 val = {lo, hi};
            *(uint2*)(ob + (size_t)n * 32 + ct2 * 16 + lk * 4) = val;
        }
    }
}

// ---------------- Kernel 5: out projection + residual, FUSED K-half merge ----------------
// A-staging reads the two unnormalized partials + L and computes (a0+a1)*rcp(L)
// on the fly: per k0 chunk, channels [k0*32, k0*32+32) == head k0 exactly.
__global__ void proj_res(const ushort_t* __restrict__ op0, const ushort_t* __restrict__ op1,
                         const float* __restrict__ lpart, const ushort_t* __restrict__ wob,
                         const float* __restrict__ x, float* __restrict__ out) {
    __shared__ ushort_t Al[64][40];
    __shared__ ushort_t Bl[64][40];
    int m0 = blockIdx.x * 64;
    int c0 = blockIdx.y * 64;
    int t = threadIdx.x, lane = t & 63, wave = t >> 6;
    int lr = lane & 15, lk = lane >> 4;
    int row = t >> 2, chk = t & 3;
    int b = m0 >> 12;
    int n = (m0 + row) & 4095;
    const ushort_t* p0 = op0 + ((size_t)(b * 8) * HW + n) * 32 + chk * 8;
    const ushort_t* p1 = op1 + ((size_t)(b * 8) * HW + n) * 32 + chk * 8;
    const float* l0 = lpart + (size_t)(b * 8) * HW + n;
    const float* l1 = lpart + (size_t)(16 + b * 8) * HW + n;
    const ushort_t* bsrc = wob + (size_t)(c0 + row) * CH + chk * 8;
    floatx4 acc[4] = {};
    uint4 ra0 = *(const uint4*)p0;
    uint4 ra1 = *(const uint4*)p1;
    float La = l0[0] + l1[0];
    uint4 rb = *(const uint4*)bsrc;
    for (int k0 = 0; k0 < 8; k0++) {
        // fused merge: a = (a0 + a1) * rcp(L), round to bf16
        float inv = __builtin_amdgcn_rcpf(La);
        uint_t u0[4] = {ra0.x, ra0.y, ra0.z, ra0.w};
        uint_t u1[4] = {ra1.x, ra1.y, ra1.z, ra1.w};
        ushort_t av[8];
        #pragma unroll
        for (int i = 0; i < 4; i++) {
            float lo = (__uint_as_float(u0[i] << 16) + __uint_as_float(u1[i] << 16)) * inv;
            float hi = (__uint_as_float(u0[i] & 0xffff0000u) + __uint_as_float(u1[i] & 0xffff0000u)) * inv;
            av[2 * i]     = f2bf(lo);
            av[2 * i + 1] = f2bf(hi);
        }
        *(uint4*)&Al[row][chk * 8] = *(uint4*)av;
        *(uint4*)&Bl[row][chk * 8] = rb;
        __syncthreads();
        if (k0 < 7) {  // prefetch next head's partials (latency hides under MFMAs)
            p0 += (size_t)HW * 32; p1 += (size_t)HW * 32;
            l0 += HW; l1 += HW;
            ra0 = *(const uint4*)p0;
            ra1 = *(const uint4*)p1;
            La  = l0[0] + l1[0];
            rb  = *(const uint4*)(bsrc + (k0 + 1) * 32);
        }
        s16x8 af = *(const s16x8*)&Al[wave * 16 + lr][lk * 8];
        #pragma unroll
        for (int ct = 0; ct < 4; ct++) {
            s16x8 bf = *(const s16x8*)&Bl[ct * 16 + lr][lk * 8];
            acc[ct] = __builtin_amdgcn_mfma_f32_16x16x32_bf16(af, bf, acc[ct], 0, 0, 0);
        }
        __syncthreads();
    }
    int mrow0 = m0 + wave * 16 + (lk << 2);
    int bb = mrow0 >> 12;
    int nn = mrow0 & 4095;
    #pragma unroll
    for (int ct = 0; ct < 4; ct++) {
        int c = c0 + ct * 16 + lr;
        const float4 xv = *(const float4*)(x + ((size_t)(bb * CH + c)) * HW + nn);
        float4 ov;
        ov.x = acc[ct][0] + xv.x;
        ov.y = acc[ct][1] + xv.y;
        ov.z = acc[ct][2] + xv.z;
        ov.w = acc[ct][3] + xv.w;
        *(float4*)(out + ((size_t)(bb * CH + c)) * HW + nn) = ov;
    }
}

extern "C" void kernel_launch(void* const* d_in, const int* in_sizes, int n_in,
                              void* d_out, int out_size, void* d_ws, size_t ws_size,
                              hipStream_t stream) {
    const float* x    = (const float*)d_in[0];
    const float* gw   = (const float*)d_in[1];
    const float* gb   = (const float*)d_in[2];
    const float* wqkv = (const float*)d_in[3];
    const float* wout = (const float*)d_in[4];
    float* out = (float*)d_out;

    char* ws = (char*)d_ws;
    float* stats = (float*)ws;
    ushort_t* xn = (ushort_t*)(ws + 512);
    size_t per = (size_t)BATCH * HW * CH;   // 2M elements (4MB bf16)
    ushort_t* q   = xn + per;
    ushort_t* k   = q + per;
    ushort_t* v   = k + per;
    ushort_t* wqb = v + per;                // 196608 elements
    ushort_t* wob = wqb + 196608;           // 65536 elements
    ushort_t* op1 = wob + 65536;            // 2M elements (4MB) - z=1 partial
    float* lpart  = (float*)(op1 + 2097152);  // 2*16*4096 f32 (512KB)
    ushort_t* op0 = xn;                     // reuse xn (dead after qkv_gemm)

    gn_stats_wcvt<<<320, 256, 0, stream>>>(x, stats, wqkv, wout, wqb);
    norm_transpose<<<dim3(64, 8, 2), 256, 0, stream>>>(x, stats, gw, gb, xn);
    qkv_gemm<<<dim3(64, 6, 2), 256, 0, stream>>>(xn, wqb, q, k, v);
    attn_f<<<dim3(32, 16, 2), 256, 0, stream>>>(q, k, v, op0, op1, lpart);
    proj_res<<<dim3(128, 4), 256, 0, stream>>>(op0, op1, lpart, wob, x, out);
}

// Round 18
// 84.179 us; speedup vs baseline: 1.0149x; 1.0149x over previous
//
#include <hip/hip_runtime.h>
#include <hip/hip_bf16.h>

#define BATCH 2
#define CH 256
#define HW 4096
#define HEADS 8
#define HDIM 32
#define GROUPS 32
#define EPS 1e-5f
#define QSCALE (0.17677669529663687f * 1.4426950408889634f)  // scale * log2(e)

typedef short s16x8 __attribute__((ext_vector_type(8)));
typedef float floatx4 __attribute__((ext_vector_type(4)));
typedef unsigned short ushort_t;
typedef unsigned int uint_t;

static __device__ __forceinline__ ushort_t f2bf(float f) {
    __hip_bfloat16 h = __float2bfloat16(f);
    return *reinterpret_cast<ushort_t*>(&h);
}
static __device__ __forceinline__ float bf2f(uint_t u) {
    return __uint_as_float(u << 16);
}

// pack two f32 -> one u32 of 2 bf16 (truncation) via single v_perm_b32
static __device__ __forceinline__ uint_t pk2(float lo, float hi) {
    return __builtin_amdgcn_perm(__float_as_uint(hi), __float_as_uint(lo), 0x07060302u);
}

static __device__ __forceinline__ void gload_lds16(const ushort_t* g, ushort_t* l) {
    __builtin_amdgcn_global_load_lds((const __attribute__((address_space(1))) void*)g,
                                     (__attribute__((address_space(3))) void*)l, 16, 0, 0);
}

// ---------------- Kernel 1: groupnorm stats + weight convert (fused launch) ----------------
__global__ void gn_stats_wcvt(const float* __restrict__ x, float* __restrict__ stats,
                              const float* __restrict__ wq, const float* __restrict__ wo,
                              ushort_t* __restrict__ wdst) {
    if (blockIdx.x >= 64) {
        int i = (blockIdx.x - 64) * 256 + threadIdx.x;  // 65536 lanes, 4 floats each
        float4 v = (i < 49152) ? ((const float4*)wq)[i] : ((const float4*)wo)[i - 49152];
        ushort_t p[4] = {f2bf(v.x), f2bf(v.y), f2bf(v.z), f2bf(v.w)};
        uint2 o;
        o.x = (uint_t)p[0] | ((uint_t)p[1] << 16);
        o.y = (uint_t)p[2] | ((uint_t)p[3] << 16);
        *(uint2*)&wdst[(size_t)i * 4] = o;
        return;
    }
    int bg = blockIdx.x;
    const float4* xv = (const float4*)(x + (size_t)bg * 8 * HW);
    int t = threadIdx.x;
    float s = 0.f, ss = 0.f;
    for (int i = t; i < 8192; i += 256) {
        float4 v = xv[i];
        s  += v.x + v.y + v.z + v.w;
        ss += v.x*v.x + v.y*v.y + v.z*v.z + v.w*v.w;
    }
    #pragma unroll
    for (int off = 32; off; off >>= 1) {
        s  += __shfl_down(s, off);
        ss += __shfl_down(ss, off);
    }
    __shared__ float rs[4], rss[4];
    int wave = t >> 6;
    if ((t & 63) == 0) { rs[wave] = s; rss[wave] = ss; }
    __syncthreads();
    if (t == 0) {
        s  = rs[0] + rs[1] + rs[2] + rs[3];
        ss = rss[0] + rss[1] + rss[2] + rss[3];
        float mu  = s / 32768.f;
        float var = ss / 32768.f - mu * mu;
        stats[bg * 2]     = mu;
        stats[bg * 2 + 1] = rsqrtf(var + EPS);
    }
}

// ---------------- Kernel 2: normalize + transpose to [b][n][c] bf16 ----------------
__global__ void norm_transpose(const float* __restrict__ x, const float* __restrict__ stats,
                               const float* __restrict__ gw, const float* __restrict__ gb,
                               ushort_t* __restrict__ xn) {
    __shared__ ushort_t tile[64][40];
    int b = blockIdx.z, c0 = blockIdx.y * 32, n0 = blockIdx.x * 64;
    int t = threadIdx.x;
    #pragma unroll
    for (int i = 0; i < 8; i++) {
        int idx = i * 256 + t;
        int c = idx >> 6, n = idx & 63;
        int cc = c0 + c;
        float mu   = stats[(b * GROUPS + (cc >> 3)) * 2];
        float rstd = stats[(b * GROUPS + (cc >> 3)) * 2 + 1];
        float v = x[((size_t)b * CH + cc) * HW + n0 + n];
        v = (v - mu) * rstd * gw[cc] + gb[cc];
        tile[n][c] = f2bf(v);
    }
    __syncthreads();
    int n = t >> 2, chk = t & 3;
    uint4 val = *(const uint4*)&tile[n][chk * 8];
    *(uint4*)(xn + ((size_t)(b * HW + n0 + n)) * CH + c0 + chk * 8) = val;
}

// ---------------- Kernel 3: QKV gemm (bf16 weights, o-tile 128, reg-prefetch) ----------------
__global__ void qkv_gemm(const ushort_t* __restrict__ xn, const ushort_t* __restrict__ wqb,
                         ushort_t* __restrict__ qo, ushort_t* __restrict__ ko,
                         ushort_t* __restrict__ vo) {
    __shared__ ushort_t Al[64][40];
    __shared__ ushort_t Bl[128][40];
    int b = blockIdx.z;
    int n0 = blockIdx.x * 64, o0 = blockIdx.y * 128;
    int t = threadIdx.x, lane = t & 63, wave = t >> 6;
    int lr = lane & 15, lk = lane >> 4;
    int row = t >> 2, chk = t & 3;
    const ushort_t* asrc = xn + ((size_t)(b * HW + n0 + row)) * CH + chk * 8;
    int s1 = t + 256;
    const ushort_t* bsrc0 = wqb + (size_t)(o0 + (t >> 2)) * CH + (t & 3) * 8;
    const ushort_t* bsrc1 = wqb + (size_t)(o0 + (s1 >> 2)) * CH + (s1 & 3) * 8;
    floatx4 acc[8] = {};
    uint4 ra  = *(const uint4*)(asrc);
    uint4 rb0 = *(const uint4*)(bsrc0);
    uint4 rb1 = *(const uint4*)(bsrc1);
    for (int k0 = 0; k0 < 8; k0++) {
        *(uint4*)&Al[row][chk * 8] = ra;
        *(uint4*)&Bl[t >> 2][(t & 3) * 8] = rb0;
        *(uint4*)&Bl[s1 >> 2][(s1 & 3) * 8] = rb1;
        __syncthreads();
        if (k0 < 7) {  // prefetch next chunk; latency hides under MFMAs
            ra  = *(const uint4*)(asrc + (k0 + 1) * 32);
            rb0 = *(const uint4*)(bsrc0 + (k0 + 1) * 32);
            rb1 = *(const uint4*)(bsrc1 + (k0 + 1) * 32);
        }
        s16x8 af = *(const s16x8*)&Al[wave * 16 + lr][lk * 8];
        #pragma unroll
        for (int ct = 0; ct < 8; ct++) {
            s16x8 bf = *(const s16x8*)&Bl[ct * 16 + lr][lk * 8];
            acc[ct] = __builtin_amdgcn_mfma_f32_16x16x32_bf16(af, bf, acc[ct], 0, 0, 0);
        }
        __syncthreads();
    }
    #pragma unroll
    for (int ct = 0; ct < 8; ct++) {
        int o = o0 + ct * 16 + lr;
        int sel = o >> 8;
        int h = (o >> 5) & 7;
        int d = o & 31;
        int nrow0 = n0 + wave * 16 + (lk << 2);
        if (sel == 0) {
            #pragma unroll
            for (int r = 0; r < 4; r++)
                qo[(((size_t)(b * HEADS + h)) * HW + nrow0 + r) * HDIM + d] =
                    f2bf(acc[ct][r] * QSCALE);
        } else if (sel == 1) {
            #pragma unroll
            for (int r = 0; r < 4; r++) {
                int tt = (nrow0 + r) & 63;
                int sg = 4 * ((tt >> 3) & 3) + 16 * ((((tt >> 2) & 1) << 1) | ((tt >> 5) & 1)) + (tt & 3);
                ko[(((size_t)(b * HEADS + h)) * HW + n0 + sg) * HDIM + d] = f2bf(acc[ct][r]);
            }
        } else {
            ushort_t pk[4];
            #pragma unroll
            for (int r = 0; r < 4; r++) pk[r] = f2bf(acc[ct][r]);
            *(uint2*)&vo[(((size_t)(b * HEADS + h)) * HDIM + d) * HW + nrow0] = *(uint2*)pk;
        }
    }
}

// ---------------- Kernel 4: flash attention (QBLK=128, K-split x2 — best measured) ----------------
__global__ void __launch_bounds__(256, 4)
attn_f(const ushort_t* __restrict__ qg, const ushort_t* __restrict__ kg,
       const ushort_t* __restrict__ vg, ushort_t* __restrict__ op0,
       ushort_t* __restrict__ op1, float* __restrict__ lpart) {
    __shared__ ushort_t Kl[2][2048];  // lane-ordered, 4KB/buf
    __shared__ ushort_t Vl[2][2048];
    const int bh = blockIdx.y;
    const int z = blockIdx.z;
    const int n0 = blockIdx.x * 128;
    const int t = threadIdx.x;
    const int lane = t & 63, w = t >> 6;
    const int lr = lane & 15, lk = lane >> 4;

    const ushort_t* kb = kg + (size_t)bh * HW * HDIM + (size_t)z * 2048 * HDIM;
    const ushort_t* vb = vg + (size_t)bh * HDIM * HW + z * 2048;

    const int lrr = t & 15, lkk = (t >> 4) & 3, wv = t >> 6;
    const ushort_t* gk = kb + ((wv << 4) + lrr) * HDIM + lkk * 8;
    const ushort_t* gv = vb + (size_t)(((t >> 7) << 4) + lrr) * HW + ((t >> 6) & 1) * 32 + lkk * 8;
    ushort_t* kd0 = &Kl[0][wv << 9]; ushort_t* kd1 = &Kl[1][wv << 9];
    ushort_t* vd0 = &Vl[0][wv << 9]; ushort_t* vd1 = &Vl[1][wv << 9];

    s16x8 qf0 = *(const s16x8*)(qg + ((size_t)bh * HW + n0 + w * 16 + lr) * HDIM + lk * 8);
    s16x8 qf1 = *(const s16x8*)(qg + ((size_t)bh * HW + n0 + 64 + w * 16 + lr) * HDIM + lk * 8);

    const s16x8 onesf = {0x3F80, 0x3F80, 0x3F80, 0x3F80, 0x3F80, 0x3F80, 0x3F80, 0x3F80};
    const floatx4 zf = {};
    floatx4 oacc[2][2] = {};   // [frag][ct2]
    floatx4 Lacc[2] = {};

    auto stage = [&](ushort_t* kdn, ushort_t* vdn) {
        gload_lds16(gk, kdn);
        gload_lds16(gv, vdn);
        gk += 64 * HDIM; gv += 64;
    };
    auto compute = [&](const ushort_t* Kb, const ushort_t* Vb) {
        floatx4 sim0[4], sim1[4];
        __builtin_amdgcn_s_setprio(1);
#pragma unroll
        for (int ct = 0; ct < 4; ct++) {
            s16x8 kf = *(const s16x8*)(Kb + ct * 512 + lane * 8);
            sim0[ct] = __builtin_amdgcn_mfma_f32_16x16x32_bf16(kf, qf0, zf, 0, 0, 0);
            sim1[ct] = __builtin_amdgcn_mfma_f32_16x16x32_bf16(kf, qf1, zf, 0, 0, 0);
        }
        __builtin_amdgcn_s_setprio(0);
        s16x8 vf[4];
#pragma unroll
        for (int i = 0; i < 4; i++)
            vf[i] = *(const s16x8*)(Vb + i * 512 + lane * 8);
        // fragment 0
        {
            s16x8 pf[2];
#pragma unroll
            for (int s = 0; s < 2; s++) {
                union { uint_t u[4]; s16x8 v; } pu;
                pu.u[0] = pk2(__builtin_amdgcn_exp2f(sim0[s][0]),     __builtin_amdgcn_exp2f(sim0[s][1]));
                pu.u[1] = pk2(__builtin_amdgcn_exp2f(sim0[s][2]),     __builtin_amdgcn_exp2f(sim0[s][3]));
                pu.u[2] = pk2(__builtin_amdgcn_exp2f(sim0[s + 2][0]), __builtin_amdgcn_exp2f(sim0[s + 2][1]));
                pu.u[3] = pk2(__builtin_amdgcn_exp2f(sim0[s + 2][2]), __builtin_amdgcn_exp2f(sim0[s + 2][3]));
                pf[s] = pu.v;
            }
            __builtin_amdgcn_s_setprio(1);
#pragma unroll
            for (int s = 0; s < 2; s++) {
                oacc[0][0] = __builtin_amdgcn_mfma_f32_16x16x32_bf16(vf[s],     pf[s], oacc[0][0], 0, 0, 0);
                oacc[0][1] = __builtin_amdgcn_mfma_f32_16x16x32_bf16(vf[2 + s], pf[s], oacc[0][1], 0, 0, 0);
                Lacc[0]    = __builtin_amdgcn_mfma_f32_16x16x32_bf16(onesf,     pf[s], Lacc[0],    0, 0, 0);
            }
            __builtin_amdgcn_s_setprio(0);
        }
        // fragment 1
        {
            s16x8 pf[2];
#pragma unroll
            for (int s = 0; s < 2; s++) {
                union { uint_t u[4]; s16x8 v; } pu;
                pu.u[0] = pk2(__builtin_amdgcn_exp2f(sim1[s][0]),     __builtin_amdgcn_exp2f(sim1[s][1]));
                pu.u[1] = pk2(__builtin_amdgcn_exp2f(sim1[s][2]),     __builtin_amdgcn_exp2f(sim1[s][3]));
                pu.u[2] = pk2(__builtin_amdgcn_exp2f(sim1[s + 2][0]), __builtin_amdgcn_exp2f(sim1[s + 2][1]));
                pu.u[3] = pk2(__builtin_amdgcn_exp2f(sim1[s + 2][2]), __builtin_amdgcn_exp2f(sim1[s + 2][3]));
                pf[s] = pu.v;
            }
            __builtin_amdgcn_s_setprio(1);
#pragma unroll
            for (int s = 0; s < 2; s++) {
                oacc[1][0] = __builtin_amdgcn_mfma_f32_16x16x32_bf16(vf[s],     pf[s], oacc[1][0], 0, 0, 0);
                oacc[1][1] = __builtin_amdgcn_mfma_f32_16x16x32_bf16(vf[2 + s], pf[s], oacc[1][1], 0, 0, 0);
                Lacc[1]    = __builtin_amdgcn_mfma_f32_16x16x32_bf16(onesf,     pf[s], Lacc[1],    0, 0, 0);
            }
            __builtin_amdgcn_s_setprio(0);
        }
    };

    stage(kd0, vd0);
    __syncthreads();
    for (int s2 = 0; s2 < 16; s2++) {
        stage(kd1, vd1);
        compute(&Kl[0][0], &Vl[0][0]);
        __syncthreads();
        if (s2 < 15) {
            stage(kd0, vd0);
            compute(&Kl[1][0], &Vl[1][0]);
            __syncthreads();
        } else {
            compute(&Kl[1][0], &Vl[1][0]);
        }
    }

    ushort_t* ob = (z ? op1 : op0) + ((size_t)bh * HW) * 32;
    float* lp = lpart + (size_t)(z * 16 + bh) * HW;
#pragma unroll
    for (int c = 0; c < 2; c++) {
        int n = n0 + c * 64 + w * 16 + lr;
        if (lk == 0) lp[n] = Lacc[c][0];
#pragma unroll
        for (int ct2 = 0; ct2 < 2; ct2++) {
            uint_t lo = (uint_t)f2bf(oacc[c][ct2][0]) | ((uint_t)f2bf(oacc[c][ct2][1]) << 16);
            uint_t hi = (uint_t)f2bf(oacc[c][ct2][2]) | ((uint_t)f2bf(oacc[c][ct2][3]) << 16);
            uint2 val = {lo, hi};
            *(uint2*)(ob + (size_t)n * 32 + ct2 * 16 + lk * 4) = val;
        }
    }
}

// ---------------- Kernel 4b: merge the two K-halves ----------------
__global__ void attn_merge(const ushort_t* __restrict__ op0, const ushort_t* __restrict__ op1,
                           const float* __restrict__ lpart, ushort_t* __restrict__ oa) {
    int idx = blockIdx.x * 256 + threadIdx.x;  // [bh][n][4 chunks of 8 d]
    int chunk = idx & 3;
    int n = (idx >> 2) & 4095;
    int bh = idx >> 14;
    size_t base = ((size_t)bh * HW + n) * 32 + chunk * 8;
    uint4 a0 = *(const uint4*)(op0 + base);
    uint4 a1 = *(const uint4*)(op1 + base);
    float L = lpart[(size_t)bh * HW + n] + lpart[(size_t)(16 + bh) * HW + n];
    float inv = 1.0f / L;
    uint_t u0[4] = {a0.x, a0.y, a0.z, a0.w}, u1[4] = {a1.x, a1.y, a1.z, a1.w};
    ushort_t res[8];
#pragma unroll
    for (int i = 0; i < 4; i++) {
        float lo = bf2f(u0[i] & 0xffffu) + bf2f(u1[i] & 0xffffu);
        float hi = bf2f(u0[i] >> 16) + bf2f(u1[i] >> 16);
        res[2 * i]     = f2bf(lo * inv);
        res[2 * i + 1] = f2bf(hi * inv);
    }
    ushort_t* dst = oa + ((size_t)((bh >> 3) * HW) + n) * CH + (bh & 7) * 32 + chunk * 8;
    *(uint4*)dst = *(uint4*)res;
}

// ---------------- Kernel 5: out projection + residual (c-tile 64, reg-prefetch) ----------------
__global__ void proj_res(const ushort_t* __restrict__ oa, const ushort_t* __restrict__ wob,
                         const float* __restrict__ x, float* __restrict__ out) {
    __shared__ ushort_t Al[64][40];
    __shared__ ushort_t Bl[64][40];
    int m0 = blockIdx.x * 64;
    int c0 = blockIdx.y * 64;
    int t = threadIdx.x, lane = t & 63, wave = t >> 6;
    int lr = lane & 15, lk = lane >> 4;
    int row = t >> 2, chk = t & 3;
    const ushort_t* asrc = oa + (size_t)(m0 + row) * CH + chk * 8;
    const ushort_t* bsrc = wob + (size_t)(c0 + row) * CH + chk * 8;
    floatx4 acc[4] = {};
    uint4 ra = *(const uint4*)(asrc);
    uint4 rb = *(const uint4*)(bsrc);
    for (int k0 = 0; k0 < 8; k0++) {
        *(uint4*)&Al[row][chk * 8] = ra;
        *(uint4*)&Bl[row][chk * 8] = rb;
        __syncthreads();
        if (k0 < 7) {
            ra = *(const uint4*)(asrc + (k0 + 1) * 32);
            rb = *(const uint4*)(bsrc + (k0 + 1) * 32);
        }
        s16x8 af = *(const s16x8*)&Al[wave * 16 + lr][lk * 8];
        #pragma unroll
        for (int ct = 0; ct < 4; ct++) {
            s16x8 bf = *(const s16x8*)&Bl[ct * 16 + lr][lk * 8];
            acc[ct] = __builtin_amdgcn_mfma_f32_16x16x32_bf16(af, bf, acc[ct], 0, 0, 0);
        }
        __syncthreads();
    }
    int mrow0 = m0 + wave * 16 + (lk << 2);
    int b = mrow0 >> 12;
    int n = mrow0 & 4095;
    #pragma unroll
    for (int ct = 0; ct < 4; ct++) {
        int c = c0 + ct * 16 + lr;
        const float4 xv = *(const float4*)(x + ((size_t)(b * CH + c)) * HW + n);
        float4 ov;
        ov.x = acc[ct][0] + xv.x;
        ov.y = acc[ct][1] + xv.y;
        ov.z = acc[ct][2] + xv.z;
        ov.w = acc[ct][3] + xv.w;
        *(float4*)(out + ((size_t)(b * CH + c)) * HW + n) = ov;
    }
}

extern "C" void kernel_launch(void* const* d_in, const int* in_sizes, int n_in,
                              void* d_out, int out_size, void* d_ws, size_t ws_size,
                              hipStream_t stream) {
    const float* x    = (const float*)d_in[0];
    const float* gw   = (const float*)d_in[1];
    const float* gb   = (const float*)d_in[2];
    const float* wqkv = (const float*)d_in[3];
    const float* wout = (const float*)d_in[4];
    float* out = (float*)d_out;

    char* ws = (char*)d_ws;
    float* stats = (float*)ws;
    ushort_t* xn = (ushort_t*)(ws + 512);
    size_t per = (size_t)BATCH * HW * CH;   // 2M elements (4MB bf16)
    ushort_t* q   = xn + per;
    ushort_t* k   = q + per;
    ushort_t* v   = k + per;
    ushort_t* oa  = v + per;
    ushort_t* wqb = oa + per;               // 196608 elements
    ushort_t* wob = wqb + 196608;           // 65536 elements
    ushort_t* op1 = wob + 65536;            // 2M elements (4MB) - z=1 partial
    float* lpart  = (float*)(op1 + 2097152);  // 2*16*4096 f32 (512KB)
    ushort_t* op0 = xn;                     // reuse xn (dead after qkv_gemm)

    gn_stats_wcvt<<<320, 256, 0, stream>>>(x, stats, wqkv, wout, wqb);
    norm_transpose<<<dim3(64, 8, 2), 256, 0, stream>>>(x, stats, gw, gb, xn);
    qkv_gemm<<<dim3(64, 6, 2), 256, 0, stream>>>(xn, wqb, q, k, v);
    attn_f<<<dim3(32, 16, 2), 256, 0, stream>>>(q, k, v, op0, op1, lpart);
    attn_merge<<<1024, 256, 0, stream>>>(op0, op1, lpart, oa);
    proj_res<<<dim3(128, 4), 256, 0, stream>>>(oa, wob, x, out);
}